// Round 11
// baseline (616.176 us; speedup 1.0000x reference)
//
#include <hip/hip_runtime.h>

#define N_NODES 50000
#define N_EDGES 800000
#define DD 128
#define GG 256
#define LL 4
#define EPSV 1e-5f
#define NB 196  // ceil(N_NODES/256)
#define AGG_BLOCKS 1024   // 4096 waves, edge-balanced node ranges
#define NWAVES 4096
#define GEMM_BLOCKS 782   // ceil(N/64)
#define WSCALE 268435456.0f  // 2^28 fixed-point for packed degree weight

typedef __attribute__((ext_vector_type(8))) short s16x8;    // 8 bf16 (4 VGPRs)
typedef __attribute__((ext_vector_type(4))) float f32x4;    // 4 fp32 acc

// ---------------- bf16 helpers ----------------
static __device__ __forceinline__ unsigned bf16pack(float a, float b) {
    unsigned ua = __float_as_uint(a), ub = __float_as_uint(b);
    ua = (ua + 0x7FFFu + ((ua >> 16) & 1u)) >> 16;  // RNE
    ub = (ub + 0x7FFFu + ((ub >> 16) & 1u)) >> 16;
    return ua | (ub << 16);
}
static __device__ __forceinline__ unsigned short bf16r(float a) {
    unsigned u = __float_as_uint(a);
    u = (u + 0x7FFFu + ((u >> 16) & 1u)) >> 16;
    return (unsigned short)u;
}
static __device__ __forceinline__ float2 bf16unpack(unsigned u) {
    float2 r;
    r.x = __uint_as_float(u << 16);
    r.y = __uint_as_float(u & 0xFFFF0000u);
    return r;
}

// ---------------- grid-wide generation barrier (co-resident blocks only) ----------------
// Proven correct in R8/R9 (mega_kernel passed). Cost scales with arrival count: 196-arrival
// (scanrow) is ~free; 1024-arrival was ~200us (R9) -> use only for <=256 blocks.
template <int NBLK>
static __device__ __forceinline__ void gridbar(unsigned* cnt, unsigned* gen) {
    __syncthreads();
    if (threadIdx.x == 0) {
        __threadfence();  // device-scope release of this block's writes
        unsigned g = __hip_atomic_load(gen, __ATOMIC_RELAXED, __HIP_MEMORY_SCOPE_AGENT);
        unsigned old = __hip_atomic_fetch_add(cnt, 1u, __ATOMIC_ACQ_REL,
                                              __HIP_MEMORY_SCOPE_AGENT);
        if (old == NBLK - 1) {
            __hip_atomic_store(cnt, 0u, __ATOMIC_RELAXED, __HIP_MEMORY_SCOPE_AGENT);
            __hip_atomic_store(gen, g + 1u, __ATOMIC_RELEASE, __HIP_MEMORY_SCOPE_AGENT);
        } else {
            while (__hip_atomic_load(gen, __ATOMIC_ACQUIRE, __HIP_MEMORY_SCOPE_AGENT) == g)
                __builtin_amdgcn_s_sleep(8);
        }
        __threadfence();  // acquire side
    }
    __syncthreads();
}

// ---------------- fused setup: wprep (blocks 0..319) + count_deg+rank (blocks 320..) ------
// u64 atomic per edge: count in [40..63], fixed-point(2^28) weight sum in [0..39].
// The returned old count is this edge's RANK among same-dst edges -> atomic-free fill later.
__global__ void prep_kernel(const float* __restrict__ preW, const float* __restrict__ convW,
                            unsigned short* __restrict__ Wf,
                            const int* __restrict__ ei, const float* __restrict__ w,
                            unsigned long long* __restrict__ cd64, int* __restrict__ rank) {
    int blk = blockIdx.x;
    if (blk < 320) {
        int idx = blk * 256 + threadIdx.x;  // 5*16384
        if (idx < 5 * 16384) {
            int l = idx >> 14, kn = idx & 16383;
            int k = kn >> 7, nn = kn & 127;
            float v = (l == 0) ? preW[kn] : convW[(l - 1) * 16384 + kn];
            int nt = nn >> 4, nl = nn & 15, kc = k >> 5, q = (k >> 3) & 3, j = k & 7;
            Wf[(size_t)l * 16384 + ((((nt * 4 + kc) * 4 + q) * 16 + nl) * 8 + j)] = bf16r(v);
        }
    } else {
        int e = (blk - 320) * 256 + threadIdx.x;
        if (e < N_EDGES) {
            int d = ei[N_EDGES + e];
            unsigned long long pack =
                (1ull << 40) | (unsigned long long)(w[e] * WSCALE);
            unsigned long long old = atomicAdd(&cd64[d], pack);
            rank[e] = (int)(old >> 40);
        }
    }
}

// ---------------- fused scan chain: blocksum + global scan + rowptr/dinv ------------------
__global__ __launch_bounds__(256) void scanrow_kernel(const unsigned long long* __restrict__ cd64,
                                                      int* __restrict__ bsums,
                                                      int* __restrict__ boffs,
                                                      int* __restrict__ rowptr,
                                                      float* __restrict__ dinv,
                                                      int* __restrict__ sem) {
    __shared__ int s[256];
    __shared__ int s2[256];
    __shared__ int amLast;
    int i = blockIdx.x * 256 + threadIdx.x;
    int t = threadIdx.x;
    unsigned long long v64 = (i < N_NODES) ? cd64[i] : 0ull;
    int c = (int)(v64 >> 40);
    s[t] = c;
    __syncthreads();
    for (int off = 1; off < 256; off <<= 1) {
        int u = (t >= off) ? s[t - off] : 0;
        __syncthreads();
        s[t] += u;
        __syncthreads();
    }
    if (t == 0) {
        bsums[blockIdx.x] = s[255];  // block total
        __threadfence();
        int old = atomicAdd(&sem[0], 1);
        amLast = (old == NB - 1) ? 1 : 0;
    }
    __syncthreads();
    if (amLast) {
        int v = (t < NB) ? __hip_atomic_load(&bsums[t], __ATOMIC_RELAXED,
                                             __HIP_MEMORY_SCOPE_AGENT)
                         : 0;
        s2[t] = v;
        __syncthreads();
        for (int off = 1; off < 256; off <<= 1) {
            int u = (t >= off) ? s2[t - off] : 0;
            __syncthreads();
            s2[t] += u;
            __syncthreads();
        }
        if (t < NB) boffs[t] = s2[t] - v;  // exclusive
        if (t == 0) {
            __threadfence();
            __hip_atomic_store(&sem[1], 1, __ATOMIC_RELEASE, __HIP_MEMORY_SCOPE_AGENT);
        }
    }
    if (t == 0) {
        while (__hip_atomic_load(&sem[1], __ATOMIC_ACQUIRE, __HIP_MEMORY_SCOPE_AGENT) == 0)
            __builtin_amdgcn_s_sleep(8);
        s2[0] = __hip_atomic_load(&boffs[blockIdx.x], __ATOMIC_RELAXED,
                                  __HIP_MEMORY_SCOPE_AGENT);
    }
    __syncthreads();
    if (i < N_NODES) {
        rowptr[i] = s2[0] + s[t] - c;
        float wsum = (float)(v64 & ((1ull << 40) - 1)) * (1.0f / WSCALE);
        dinv[i] = rsqrtf(fmaxf(wsum + 2.0f, EPSV));  // self-loop weight 2.0
    }
    if (blockIdx.x == 0 && t == 0) rowptr[N_NODES] = N_EDGES;
}

// fused: atomic-free fill via rank (blocks 0..3124) + wsplit (blocks 3125..)
// edat packed 4B: low 16 = src (N<65536), high 16 = bf16(edge weight)
__global__ void fillws_kernel(const int* __restrict__ ei, const float* __restrict__ w,
                              const int* __restrict__ rank, unsigned* __restrict__ edat,
                              const int* __restrict__ rowptr, int* __restrict__ wsplit) {
    int blk = blockIdx.x;
    if (blk < 3125) {
        int e = blk * 256 + threadIdx.x;
        if (e < N_EDGES) {
            int s_ = ei[e];
            int d = ei[N_EDGES + e];
            int pos = rowptr[d] + rank[e];
            edat[pos] = (unsigned)s_ | ((unsigned)bf16r(w[e]) << 16);
        }
    } else {
        int wdx = (blk - 3125) * 256 + threadIdx.x;
        if (wdx <= NWAVES) {
            const long long totalW = (long long)N_EDGES + 6ll * N_NODES;
            long long target = (totalW * (long long)wdx) / NWAVES;
            int a = 0, b = N_NODES;
            while (a < b) {
                int m = (a + b) >> 1;
                long long wk = (long long)rowptr[m] + 6ll * m;
                if (wk < target) a = m + 1; else b = m;
            }
            wsplit[wdx] = a;
        }
    }
}

// ---------------- MFMA GEMM, register-direct: out[n,128] = act(A)[n,128] @ W[128,128] ----
// (R8/R9 mega-kernel phase arithmetic confirmed these run ~10us each — not a bottleneck.)
template <bool INBF16, bool AFFINE, bool STATS, bool SCALE>
__global__ __launch_bounds__(256) void gemm_mfma(const void* __restrict__ Av, int n,
                                                 const uint4* __restrict__ Wf,
                                                 const float* __restrict__ stats_in,
                                                 const float* __restrict__ bn_sc,
                                                 const float* __restrict__ bn_bi,
                                                 const float* __restrict__ bias,
                                                 const float* __restrict__ dinv,
                                                 unsigned* __restrict__ outv,
                                                 float* __restrict__ stats_out) {
    __shared__ float chalf[64 * 68];        // C bounce, one 64-col half at a time
    __shared__ float affg[128], affb[128];  // affine coefs | staged bias | stats scratch
    int t = threadIdx.x;
    int row0 = blockIdx.x * 64;

    if (AFFINE) {
        if (t < 128) {
            float mean = stats_in[t] * (1.0f / N_NODES);
            float var = fmaxf(stats_in[128 + t] * (1.0f / N_NODES) - mean * mean, 0.f);
            float g = bn_sc[t] * rsqrtf(var + EPSV);
            affg[t] = g;
            affb[t] = bn_bi[t] - mean * g;
        }
    } else {
        if (t < 128) affg[t] = bias[t];
    }
    __syncthreads();

    int wv = t >> 6, lane = t & 63, q = lane >> 4, ml = lane & 15;
    int arow = row0 + wv * 16 + ml;
    bool rok = arow < n;
    f32x4 acc[8];
#pragma unroll
    for (int nt = 0; nt < 8; nt++) acc[nt] = (f32x4){0.f, 0.f, 0.f, 0.f};
    const unsigned short* Wg = (const unsigned short*)Wf;

#pragma unroll
    for (int kc = 0; kc < 4; kc++) {
        float va[8];
        if (INBF16) {
            uint4 p = make_uint4(0u, 0u, 0u, 0u);
            if (rok)
                p = *(const uint4*)&((const unsigned*)Av)[(size_t)arow * 64 + kc * 16 + q * 4];
            float2 a0 = bf16unpack(p.x), a1 = bf16unpack(p.y);
            float2 a2 = bf16unpack(p.z), a3 = bf16unpack(p.w);
            va[0] = a0.x; va[1] = a0.y; va[2] = a1.x; va[3] = a1.y;
            va[4] = a2.x; va[5] = a2.y; va[6] = a3.x; va[7] = a3.y;
        } else {
            const float* Ax = (const float*)Av;
            float4 x0 = make_float4(0.f, 0.f, 0.f, 0.f), x1 = x0;
            if (rok) {
                x0 = *(const float4*)&Ax[(size_t)arow * 128 + kc * 32 + q * 8];
                x1 = *(const float4*)&Ax[(size_t)arow * 128 + kc * 32 + q * 8 + 4];
            }
            va[0] = x0.x; va[1] = x0.y; va[2] = x0.z; va[3] = x0.w;
            va[4] = x1.x; va[5] = x1.y; va[6] = x1.z; va[7] = x1.w;
        }
        if (AFFINE) {
            int cb = kc * 32 + q * 8;
            float4 g0 = *(float4*)&affg[cb], g1 = *(float4*)&affg[cb + 4];
            float4 b0 = *(float4*)&affb[cb], b1 = *(float4*)&affb[cb + 4];
            va[0] = fmaxf(va[0] * g0.x + b0.x, 0.f);
            va[1] = fmaxf(va[1] * g0.y + b0.y, 0.f);
            va[2] = fmaxf(va[2] * g0.z + b0.z, 0.f);
            va[3] = fmaxf(va[3] * g0.w + b0.w, 0.f);
            va[4] = fmaxf(va[4] * g1.x + b1.x, 0.f);
            va[5] = fmaxf(va[5] * g1.y + b1.y, 0.f);
            va[6] = fmaxf(va[6] * g1.z + b1.z, 0.f);
            va[7] = fmaxf(va[7] * g1.w + b1.w, 0.f);
        }
        uint4 au;
        au.x = bf16pack(va[0], va[1]);
        au.y = bf16pack(va[2], va[3]);
        au.z = bf16pack(va[4], va[5]);
        au.w = bf16pack(va[6], va[7]);
        s16x8 a = *(s16x8*)&au;
#pragma unroll
        for (int nt = 0; nt < 8; nt++) {
            s16x8 b = *(const s16x8*)&Wg[(((nt * 4 + kc) * 4 + q) * 16 + ml) * 8];
            acc[nt] = __builtin_amdgcn_mfma_f32_16x16x32_bf16(a, b, acc[nt], 0, 0, 0);
        }
    }

    // epilogue: two 64-col halves through LDS
    float csum[2][4] = {{0, 0, 0, 0}, {0, 0, 0, 0}};
    float csq[2][4] = {{0, 0, 0, 0}, {0, 0, 0, 0}};
    int cb = (t & 15) * 4;
#pragma unroll
    for (int h = 0; h < 2; ++h) {
        if (h) __syncthreads();  // protect chalf reuse
#pragma unroll
        for (int nt = 0; nt < 4; ++nt)
#pragma unroll
            for (int rr = 0; rr < 4; ++rr)
                chalf[(wv * 16 + q * 4 + rr) * 68 + nt * 16 + ml] = acc[h * 4 + nt][rr];
        __syncthreads();
        int c = h * 64 + cb;
#pragma unroll
        for (int it = 0; it < 4; ++it) {
            int r = (t >> 4) + it * 16;
            int row = row0 + r;
            if (row < n) {
                float4 v = *(float4*)&chalf[r * 68 + cb];
                if (!AFFINE) {
                    v.x += affg[c];
                    v.y += affg[c + 1];
                    v.z += affg[c + 2];
                    v.w += affg[c + 3];
                }
                if (STATS) {
                    csum[h][0] += v.x; csq[h][0] += v.x * v.x;
                    csum[h][1] += v.y; csq[h][1] += v.y * v.y;
                    csum[h][2] += v.z; csq[h][2] += v.z * v.z;
                    csum[h][3] += v.w; csq[h][3] += v.w * v.w;
                }
                float dv = SCALE ? dinv[row] : 1.0f;
                uint2 p;
                p.x = bf16pack(v.x * dv, v.y * dv);
                p.y = bf16pack(v.z * dv, v.w * dv);
                *(uint2*)&outv[(size_t)row * 64 + (c >> 1)] = p;
            }
        }
    }
    if (STATS) {
        __syncthreads();
        if (t < 128) { affg[t] = 0.f; affb[t] = 0.f; }
        __syncthreads();
#pragma unroll
        for (int h = 0; h < 2; ++h)
#pragma unroll
            for (int j = 0; j < 4; ++j) {
                atomicAdd(&affg[h * 64 + cb + j], csum[h][j]);
                atomicAdd(&affb[h * 64 + cb + j], csq[h][j]);
            }
        __syncthreads();
        if (t < 128) {
            atomicAdd(&stats_out[t], affg[t]);
            atomicAdd(&stats_out[128 + t], affb[t]);
        }
    }
}

// ---------------- aggregation: 32-wide gather on h' = dinv*h ---------------------------
// out[i] = bf16( dinv[i]*( sum_e w_e*h'[src] + 2*h'[i] ) + bias )
// Latency x concurrency limited: 8->16-wide gave 71->64us (BW 1.94->2.10 TB/s, FETCH flat).
// 32-wide = 8 gathers in flight/wave at FIXED 4096 waves; guard-lane waste (~50% at
// Poisson-16 degrees) hits cache-hot row 0 — costs only issue bandwidth (75% headroom).
__global__ __launch_bounds__(256) void aggv_kernel(const unsigned* __restrict__ hT,
                                                   const int* __restrict__ rowptr,
                                                   const int* __restrict__ wsplit,
                                                   const unsigned* __restrict__ edat,
                                                   const float* __restrict__ dinv,
                                                   const float* __restrict__ convb,
                                                   unsigned* __restrict__ out,
                                                   float* __restrict__ stats) {
    __shared__ float sbuf[256];
    int t = threadIdx.x;
    int wave = t >> 6, lane = t & 63;
    int g = lane >> 4, u = lane & 15;
    int wid = blockIdx.x * 4 + wave;
    int i0 = wsplit[wid];
    int i1 = wsplit[wid + 1];
    float4 bb0 = *(const float4*)&convb[u * 8];
    float4 bb1 = *(const float4*)&convb[u * 8 + 4];
    float ssum[4] = {0, 0, 0, 0}, ssq[4] = {0, 0, 0, 0};
    for (int i = i0; i < i1; ++i) {
        int e = rowptr[i], end = rowptr[i + 1];
        uint4 hs = *(const uint4*)&hT[(size_t)i * 64 + u * 4];
        float di = dinv[i];
        float acc[8];
#pragma unroll
        for (int k = 0; k < 8; k++) acc[k] = 0.f;
        // 32 edges/iter: 8 independent edat loads + 8 independent row gathers in flight.
        for (int eb = e; eb < end; eb += 32) {
            unsigned dd[8];
            uint4 hv[8];
#pragma unroll
            for (int s = 0; s < 8; ++s) {
                int ee = eb + s * 4 + g;
                dd[s] = (ee < end) ? __builtin_nontemporal_load(edat + ee) : 0u;
            }
#pragma unroll
            for (int s = 0; s < 8; ++s)
                hv[s] = *(const uint4*)&hT[(size_t)(dd[s] & 0xFFFFu) * 64 + u * 4];
#pragma unroll
            for (int s = 0; s < 8; ++s) {
                float nrm = __uint_as_float(dd[s] & 0xFFFF0000u);
                float2 p0 = bf16unpack(hv[s].x), p1 = bf16unpack(hv[s].y);
                float2 p2 = bf16unpack(hv[s].z), p3 = bf16unpack(hv[s].w);
                acc[0] += nrm * p0.x; acc[1] += nrm * p0.y;
                acc[2] += nrm * p1.x; acc[3] += nrm * p1.y;
                acc[4] += nrm * p2.x; acc[5] += nrm * p2.y;
                acc[6] += nrm * p3.x; acc[7] += nrm * p3.y;
            }
        }
#pragma unroll
        for (int k = 0; k < 8; k++) {
            acc[k] += __shfl_xor(acc[k], 16);
            acc[k] += __shfl_xor(acc[k], 32);
        }
        {
            float2 p0 = bf16unpack(hs.x), p1 = bf16unpack(hs.y);
            float2 p2 = bf16unpack(hs.z), p3 = bf16unpack(hs.w);
            acc[0] += 2.f * p0.x; acc[1] += 2.f * p0.y;
            acc[2] += 2.f * p1.x; acc[3] += 2.f * p1.y;
            acc[4] += 2.f * p2.x; acc[5] += 2.f * p2.y;
            acc[6] += 2.f * p3.x; acc[7] += 2.f * p3.y;
        }
        if (g < 2) {
            float4 wv;
            if (g == 0)
                wv = make_float4(di * acc[0] + bb0.x, di * acc[1] + bb0.y,
                                 di * acc[2] + bb0.z, di * acc[3] + bb0.w);
            else
                wv = make_float4(di * acc[4] + bb1.x, di * acc[5] + bb1.y,
                                 di * acc[6] + bb1.z, di * acc[7] + bb1.w);
            ssum[0] += wv.x; ssq[0] += wv.x * wv.x;
            ssum[1] += wv.y; ssq[1] += wv.y * wv.y;
            ssum[2] += wv.z; ssq[2] += wv.z * wv.z;
            ssum[3] += wv.w; ssq[3] += wv.w * wv.w;
            uint2 p;
            p.x = bf16pack(wv.x, wv.y);
            p.y = bf16pack(wv.z, wv.w);
            *(uint2*)&out[(size_t)i * 64 + u * 4 + g * 2] = p;
        }
    }
    sbuf[t] = 0.f;
    __syncthreads();
    if (g < 2) {
        int f = u * 8 + g * 4;
#pragma unroll
        for (int j = 0; j < 4; j++) {
            atomicAdd(&sbuf[f + j], ssum[j]);
            atomicAdd(&sbuf[128 + f + j], ssq[j]);
        }
    }
    __syncthreads();
    atomicAdd(&stats[t], sbuf[t]);
}

// ---------------- fused tail: pool + post-FC GEMM + output head (one kernel) --------------
// 256 blocks, co-resident (64KB LDS -> 2 blocks/CU = 512 slots). Two 256-arrival barriers
// (gridbar pattern proven in R8/R9; scanrow's 196-arrival version is ~free).
__global__ __launch_bounds__(256) void tail_kernel(
    const unsigned* __restrict__ h, const float* __restrict__ stats4,
    const float* __restrict__ bn_s3, const float* __restrict__ bn_b3,
    const int* __restrict__ batch, const float* __restrict__ postW,
    const float* __restrict__ postb, const float* __restrict__ post_bn_s,
    const float* __restrict__ post_bn_b, const float* __restrict__ outW,
    const float* __restrict__ outb, float* __restrict__ pooled, float* __restrict__ Z,
    float* __restrict__ stats5, float* __restrict__ out, int* __restrict__ sem) {
    __shared__ float smem[16384];  // 64KB: phase2 As|Ws; phase1/3 scratch
    unsigned* cnt = (unsigned*)&sem[4];
    unsigned* gen = (unsigned*)&sem[5];
    int t = threadIdx.x;
    int blk = blockIdx.x;

    // ---- phase 1: pooled[g] = mean over graph g of relu(bn4(h)) ----
    {
        int g = blk;
        int f = t & 127, half = t >> 7;
        float mean = stats4[f] * (1.0f / N_NODES);
        float var = fmaxf(stats4[128 + f] * (1.0f / N_NODES) - mean * mean, 0.f);
        float ga = bn_s3[f] * rsqrtf(var + EPSV);
        float gb = bn_b3[f] - mean * ga;
        int lo, hi;
        {
            int a = 0, b = N_NODES;
            while (a < b) { int m = (a + b) >> 1; if (batch[m] < g) a = m + 1; else b = m; }
            lo = a;
            b = N_NODES;
            while (a < b) { int m = (a + b) >> 1; if (batch[m] < g + 1) a = m + 1; else b = m; }
            hi = a;
        }
        float acc = 0.f;
        for (int i = lo + half; i < hi; i += 2) {
            unsigned v = h[(size_t)i * 64 + (f >> 1)];
            float hv = (f & 1) ? __uint_as_float(v & 0xFFFF0000u) : __uint_as_float(v << 16);
            acc += fmaxf(hv * ga + gb, 0.f);
        }
        smem[t] = acc;
        __syncthreads();
        if (t < 128)
            pooled[(size_t)g * 128 + t] = (smem[t] + smem[t + 128]) / fmaxf((float)(hi - lo), 1.0f);
    }
    gridbar<GG>(cnt, gen);

    // ---- phase 2 (blocks 0..7): Z = pooled @ postW + postb, stats5 ----
    if (blk < 8) {
        float* As = smem;           // [128][64] col-major-ish staging
        float* Ws = smem + 8192;    // [128][64]
        int row0 = (blk >> 1) * 64;
        int col0 = (blk & 1) * 64;
        {
            int rsub = t >> 5;
            int k4 = (t & 31) * 4;
            for (int it = 0; it < 8; ++it) {
                int r = it * 8 + rsub;
                float4 v = *(const float4*)&pooled[(size_t)(row0 + r) * 128 + k4];
                As[(k4 + 0) * 64 + r] = v.x;
                As[(k4 + 1) * 64 + r] = v.y;
                As[(k4 + 2) * 64 + r] = v.z;
                As[(k4 + 3) * 64 + r] = v.w;
            }
        }
        {
            int krow = t >> 4;
            int c4 = (t & 15) * 4;
            for (int it = 0; it < 8; ++it) {
                int k = it * 16 + krow;
                *(float4*)&Ws[k * 64 + c4] = *(const float4*)&postW[k * 128 + col0 + c4];
            }
        }
        __syncthreads();
        int ty = t >> 4, tx = t & 15;
        float acc[4][4];
#pragma unroll
        for (int i = 0; i < 4; i++)
#pragma unroll
            for (int j = 0; j < 4; j++) acc[i][j] = 0.f;
#pragma unroll 4
        for (int k = 0; k < 128; k++) {
            float4 a = *(const float4*)&As[k * 64 + ty * 4];
            float4 b = *(const float4*)&Ws[k * 64 + tx * 4];
            float av[4] = {a.x, a.y, a.z, a.w};
            float bv[4] = {b.x, b.y, b.z, b.w};
#pragma unroll
            for (int i = 0; i < 4; i++)
#pragma unroll
                for (int j = 0; j < 4; j++) acc[i][j] += av[i] * bv[j];
        }
        float csum[4] = {0, 0, 0, 0}, csq[4] = {0, 0, 0, 0};
#pragma unroll
        for (int i = 0; i < 4; i++) {
            int row = row0 + ty * 4 + i;
#pragma unroll
            for (int j = 0; j < 4; j++) {
                float v = acc[i][j] + postb[col0 + tx * 4 + j];
                Z[(size_t)row * 128 + col0 + tx * 4 + j] = v;
                csum[j] += v; csq[j] += v * v;
            }
        }
        float* ps = As;
        float* pq = As + 64;
        __syncthreads();
        if (t < 64) { ps[t] = 0.f; pq[t] = 0.f; }
        __syncthreads();
#pragma unroll
        for (int j = 0; j < 4; j++) {
            atomicAdd(&ps[tx * 4 + j], csum[j]);
            atomicAdd(&pq[tx * 4 + j], csq[j]);
        }
        __syncthreads();
        if (t < 64) {
            atomicAdd(&stats5[col0 + t], ps[t]);
            atomicAdd(&stats5[128 + col0 + t], pq[t]);
        }
    }
    gridbar<GG>(cnt, gen);

    // ---- phase 3: out[g] = relu(bn5(Z[g])) . outW + outb ----
    if (t < 64) {
        int g = blk;
        int lane = t;
        int d0 = lane * 2;
        const float invN = 1.0f / GG;
        float m0 = stats5[d0] * invN, m1 = stats5[d0 + 1] * invN;
        float v0 = fmaxf(stats5[128 + d0] * invN - m0 * m0, 0.f);
        float v1 = fmaxf(stats5[128 + d0 + 1] * invN - m1 * m1, 0.f);
        float ga0 = post_bn_s[d0] * rsqrtf(v0 + EPSV), gb0 = post_bn_b[d0] - m0 * ga0;
        float ga1 = post_bn_s[d0 + 1] * rsqrtf(v1 + EPSV), gb1 = post_bn_b[d0 + 1] - m1 * ga1;
        float2 z = *(const float2*)&Z[(size_t)g * 128 + d0];
        float s = fmaxf(z.x * ga0 + gb0, 0.f) * outW[d0] +
                  fmaxf(z.y * ga1 + gb1, 0.f) * outW[d0 + 1];
        for (int off = 32; off; off >>= 1) s += __shfl_down(s, off);
        if (lane == 0) out[g] = s + outb[0];
    }
}

// ---------------- host ----------------
extern "C" void kernel_launch(void* const* d_in, const int* in_sizes, int n_in,
                              void* d_out, int out_size, void* d_ws, size_t ws_size,
                              hipStream_t stream) {
    const float* x         = (const float*)d_in[0];
    const int*   ei        = (const int*)d_in[1];
    const float* ew        = (const float*)d_in[2];
    const int*   batch     = (const int*)d_in[3];
    const float* pre_W     = (const float*)d_in[4];
    const float* pre_b     = (const float*)d_in[5];
    const float* pre_bn_s  = (const float*)d_in[6];
    const float* pre_bn_b  = (const float*)d_in[7];
    const float* convW     = (const float*)d_in[8];
    const float* convb     = (const float*)d_in[9];
    const float* bn_s      = (const float*)d_in[10];
    const float* bn_b      = (const float*)d_in[11];
    const float* post_W    = (const float*)d_in[12];
    const float* post_b    = (const float*)d_in[13];
    const float* post_bn_s = (const float*)d_in[14];
    const float* post_bn_b = (const float*)d_in[15];
    const float* out_W     = (const float*)d_in[16];
    const float* out_b     = (const float*)d_in[17];

    float* ws = (float*)d_ws;
    unsigned long long* cd64 = (unsigned long long*)ws;  // N u64 = 2N floats (zeroed)
    float* stats  = ws + 2 * N_NODES;          // 6*256 (zeroed)
    int*   sem    = (int*)(stats + 6 * 256);   // 8 ints (zeroed: scanrow sem + tail barrier)
    size_t zero_floats = 2 * N_NODES + 6 * 256 + 8;
    float* pooled = (float*)(sem + 8);         // 256*128 (fully written by tail phase 1)
    float* Z      = pooled + GG * 128;         // 256*128 (fully written by tail phase 2)
    int*   rowptr = (int*)(Z + GG * 128);      // N+1
    int*   bsums  = rowptr + N_NODES + 1;      // NB
    int*   boffs  = bsums + NB;                // NB
    int*   wsplit = boffs + NB;                // NWAVES+1
    int*   rank   = wsplit + NWAVES + 1;       // E
    size_t woff = (size_t)((float*)(rank + N_EDGES) - ws);
    woff = (woff + 3) & ~(size_t)3;            // 16B align for uint4
    unsigned short* Wf = (unsigned short*)(ws + woff);  // 5*16384 ushort = 40960 floats
    size_t eoff = woff + 40960;
    unsigned* edat = (unsigned*)(ws + eoff);   // E u32 (packed src|bf16w)
    float* dinv   = ws + eoff + (size_t)N_EDGES;  // N
    size_t off = eoff + (size_t)N_EDGES + N_NODES;
    off = (off + 3) & ~(size_t)3;              // 16B align
    unsigned* hA = (unsigned*)(ws + off);          // N*64 u32 packed bf16
    unsigned* hB = hA + (size_t)N_NODES * 64;      // N*64 u32 packed bf16

    hipMemsetAsync(d_ws, 0, zero_floats * sizeof(float), stream);
    prep_kernel<<<320 + 3125, 256, 0, stream>>>(pre_W, convW, Wf, ei, ew, cd64, rank);
    scanrow_kernel<<<NB, 256, 0, stream>>>(cd64, bsums, boffs, rowptr, dinv, sem);
    fillws_kernel<<<3125 + 17, 256, 0, stream>>>(ei, ew, rank, edat, rowptr, wsplit);

    // pre FC: hA = bf16(x @ pre_W + pre_b) (MFMA bf16), stats0 on fp32 values
    gemm_mfma<false, false, true, false><<<GEMM_BLOCKS, 256, 0, stream>>>(
        (const void*)x, N_NODES, (const uint4*)Wf, nullptr, nullptr, nullptr, pre_b, nullptr,
        hA, stats + 0);
    for (int l = 0; l < LL; l++) {
        const float* sc = (l == 0) ? pre_bn_s : bn_s + (l - 1) * 128;
        const float* bi = (l == 0) ? pre_bn_b : bn_b + (l - 1) * 128;
        // hB = bf16(dinv[row] * (relu(bn(hA)) @ convW[l]))  (h' = dinv*h)
        gemm_mfma<true, true, false, true><<<GEMM_BLOCKS, 256, 0, stream>>>(
            (const void*)hA, N_NODES, (const uint4*)(Wf + (size_t)(1 + l) * 16384),
            stats + l * 256, sc, bi, nullptr, dinv, hB, nullptr);
        // hA = bf16(dinv[i]*(gather(hB) + 2*h'[i]) + convb[l]), stats_{l+1}
        aggv_kernel<<<AGG_BLOCKS, 256, 0, stream>>>(hB, rowptr, wsplit, edat, dinv,
                                                    convb + l * 128, hA, stats + (l + 1) * 256);
    }
    // fused tail: pool -> postFC(+stats5) -> output head (one kernel, 2 internal barriers)
    tail_kernel<<<GG, 256, 0, stream>>>(hA, stats + 4 * 256, bn_s + 3 * 128, bn_b + 3 * 128,
                                        batch, post_W, post_b, post_bn_s, post_bn_b, out_W,
                                        out_b, pooled, Z, stats + 5 * 256, (float*)d_out, sem);
}

// Round 12
// 546.045 us; speedup vs baseline: 1.1284x; 1.1284x over previous
//
#include <hip/hip_runtime.h>

#define N_NODES 50000
#define N_EDGES 800000
#define DD 128
#define GG 256
#define LL 4
#define EPSV 1e-5f
#define NB 196  // ceil(N_NODES/256)
#define AGG_BLOCKS 1024   // 4096 waves, edge-balanced node ranges
#define NWAVES 4096
#define GEMM_BLOCKS 782   // ceil(N/64)
#define WSCALE 268435456.0f  // 2^28 fixed-point for packed degree weight

typedef __attribute__((ext_vector_type(8))) short s16x8;    // 8 bf16 (4 VGPRs)
typedef __attribute__((ext_vector_type(4))) float f32x4;    // 4 fp32 acc

// ---------------- bf16 helpers ----------------
static __device__ __forceinline__ unsigned bf16pack(float a, float b) {
    unsigned ua = __float_as_uint(a), ub = __float_as_uint(b);
    ua = (ua + 0x7FFFu + ((ua >> 16) & 1u)) >> 16;  // RNE
    ub = (ub + 0x7FFFu + ((ub >> 16) & 1u)) >> 16;
    return ua | (ub << 16);
}
static __device__ __forceinline__ unsigned short bf16r(float a) {
    unsigned u = __float_as_uint(a);
    u = (u + 0x7FFFu + ((u >> 16) & 1u)) >> 16;
    return (unsigned short)u;
}
static __device__ __forceinline__ float2 bf16unpack(unsigned u) {
    float2 r;
    r.x = __uint_as_float(u << 16);
    r.y = __uint_as_float(u & 0xFFFF0000u);
    return r;
}

// ---------------- fused setup: wprep (blocks 0..319) + count_deg+rank (blocks 320..) ------
// u64 atomic per edge: count in [40..63], fixed-point(2^28) weight sum in [0..39].
// The returned old count is this edge's RANK among same-dst edges -> atomic-free fill later.
__global__ void prep_kernel(const float* __restrict__ preW, const float* __restrict__ convW,
                            unsigned short* __restrict__ Wf,
                            const int* __restrict__ ei, const float* __restrict__ w,
                            unsigned long long* __restrict__ cd64, int* __restrict__ rank) {
    int blk = blockIdx.x;
    if (blk < 320) {
        int idx = blk * 256 + threadIdx.x;  // 5*16384
        if (idx < 5 * 16384) {
            int l = idx >> 14, kn = idx & 16383;
            int k = kn >> 7, nn = kn & 127;
            float v = (l == 0) ? preW[kn] : convW[(l - 1) * 16384 + kn];
            int nt = nn >> 4, nl = nn & 15, kc = k >> 5, q = (k >> 3) & 3, j = k & 7;
            Wf[(size_t)l * 16384 + ((((nt * 4 + kc) * 4 + q) * 16 + nl) * 8 + j)] = bf16r(v);
        }
    } else {
        int e = (blk - 320) * 256 + threadIdx.x;
        if (e < N_EDGES) {
            int d = ei[N_EDGES + e];
            unsigned long long pack =
                (1ull << 40) | (unsigned long long)(w[e] * WSCALE);
            unsigned long long old = atomicAdd(&cd64[d], pack);
            rank[e] = (int)(old >> 40);
        }
    }
}

// ---------------- blocksum: per-block node-count sums ----------------
// (Barrier-free scan chain: R11 showed N-arrival device barriers cost ~200ns/arrival —
//  196 arrivals ~= 40us hidden in the old fused scanrow. Two plain kernels instead.)
__global__ __launch_bounds__(256) void blocksum_kernel(const unsigned long long* __restrict__ cd64,
                                                       int* __restrict__ bsums) {
    int i = blockIdx.x * 256 + threadIdx.x;
    int v = (i < N_NODES) ? (int)(cd64[i] >> 40) : 0;
    for (int off = 32; off; off >>= 1) v += __shfl_down(v, off);
    __shared__ int s[4];
    if ((threadIdx.x & 63) == 0) s[threadIdx.x >> 6] = v;
    __syncthreads();
    if (threadIdx.x == 0) bsums[blockIdx.x] = s[0] + s[1] + s[2] + s[3];
}

// ---------------- rowptr2: redundant bsums scan per block + per-node scan ----------------
// Every block scans all 196 bsums in LDS (L2-hot, ~1us) -> its own offset. No atomics,
// no semaphore; the kernel boundary provides bsums visibility.
__global__ __launch_bounds__(256) void rowptr2_kernel(const unsigned long long* __restrict__ cd64,
                                                      const int* __restrict__ bsums,
                                                      int* __restrict__ rowptr,
                                                      float* __restrict__ dinv) {
    __shared__ int s[256];
    __shared__ int s2[256];
    int i = blockIdx.x * 256 + threadIdx.x;
    int t = threadIdx.x;
    unsigned long long v64 = (i < N_NODES) ? cd64[i] : 0ull;
    int c = (int)(v64 >> 40);
    s[t] = c;
    s2[t] = (t < NB) ? bsums[t] : 0;
    __syncthreads();
    for (int off = 1; off < 256; off <<= 1) {
        int u = (t >= off) ? s[t - off] : 0;
        int u2 = (t >= off) ? s2[t - off] : 0;
        __syncthreads();
        s[t] += u;
        s2[t] += u2;
        __syncthreads();
    }
    // exclusive block offset for this block
    int boff = (blockIdx.x == 0) ? 0 : s2[blockIdx.x - 1];
    if (i < N_NODES) {
        rowptr[i] = boff + s[t] - c;
        float wsum = (float)(v64 & ((1ull << 40) - 1)) * (1.0f / WSCALE);
        dinv[i] = rsqrtf(fmaxf(wsum + 2.0f, EPSV));  // self-loop weight 2.0
    }
    if (blockIdx.x == 0 && t == 0) rowptr[N_NODES] = N_EDGES;
}

// fused: atomic-free fill via rank (blocks 0..3124) + wsplit (blocks 3125..)
// edat packed 4B: low 16 = src (N<65536), high 16 = bf16(edge weight)
__global__ void fillws_kernel(const int* __restrict__ ei, const float* __restrict__ w,
                              const int* __restrict__ rank, unsigned* __restrict__ edat,
                              const int* __restrict__ rowptr, int* __restrict__ wsplit) {
    int blk = blockIdx.x;
    if (blk < 3125) {
        int e = blk * 256 + threadIdx.x;
        if (e < N_EDGES) {
            int s_ = ei[e];
            int d = ei[N_EDGES + e];
            int pos = rowptr[d] + rank[e];
            edat[pos] = (unsigned)s_ | ((unsigned)bf16r(w[e]) << 16);
        }
    } else {
        int wdx = (blk - 3125) * 256 + threadIdx.x;
        if (wdx <= NWAVES) {
            const long long totalW = (long long)N_EDGES + 6ll * N_NODES;
            long long target = (totalW * (long long)wdx) / NWAVES;
            int a = 0, b = N_NODES;
            while (a < b) {
                int m = (a + b) >> 1;
                long long wk = (long long)rowptr[m] + 6ll * m;
                if (wk < target) a = m + 1; else b = m;
            }
            wsplit[wdx] = a;
        }
    }
}

// ---------------- MFMA GEMM, register-direct: out[n,128] = act(A)[n,128] @ W[128,128] ----
template <bool INBF16, bool AFFINE, bool STATS, bool SCALE>
__global__ __launch_bounds__(256) void gemm_mfma(const void* __restrict__ Av, int n,
                                                 const uint4* __restrict__ Wf,
                                                 const float* __restrict__ stats_in,
                                                 const float* __restrict__ bn_sc,
                                                 const float* __restrict__ bn_bi,
                                                 const float* __restrict__ bias,
                                                 const float* __restrict__ dinv,
                                                 unsigned* __restrict__ outv,
                                                 float* __restrict__ stats_out) {
    __shared__ float chalf[64 * 68];        // C bounce, one 64-col half at a time
    __shared__ float affg[128], affb[128];  // affine coefs | staged bias | stats scratch
    int t = threadIdx.x;
    int row0 = blockIdx.x * 64;

    if (AFFINE) {
        if (t < 128) {
            float mean = stats_in[t] * (1.0f / N_NODES);
            float var = fmaxf(stats_in[128 + t] * (1.0f / N_NODES) - mean * mean, 0.f);
            float g = bn_sc[t] * rsqrtf(var + EPSV);
            affg[t] = g;
            affb[t] = bn_bi[t] - mean * g;
        }
    } else {
        if (t < 128) affg[t] = bias[t];
    }
    __syncthreads();

    int wv = t >> 6, lane = t & 63, q = lane >> 4, ml = lane & 15;
    int arow = row0 + wv * 16 + ml;
    bool rok = arow < n;
    f32x4 acc[8];
#pragma unroll
    for (int nt = 0; nt < 8; nt++) acc[nt] = (f32x4){0.f, 0.f, 0.f, 0.f};
    const unsigned short* Wg = (const unsigned short*)Wf;

#pragma unroll
    for (int kc = 0; kc < 4; kc++) {
        float va[8];
        if (INBF16) {
            uint4 p = make_uint4(0u, 0u, 0u, 0u);
            if (rok)
                p = *(const uint4*)&((const unsigned*)Av)[(size_t)arow * 64 + kc * 16 + q * 4];
            float2 a0 = bf16unpack(p.x), a1 = bf16unpack(p.y);
            float2 a2 = bf16unpack(p.z), a3 = bf16unpack(p.w);
            va[0] = a0.x; va[1] = a0.y; va[2] = a1.x; va[3] = a1.y;
            va[4] = a2.x; va[5] = a2.y; va[6] = a3.x; va[7] = a3.y;
        } else {
            const float* Ax = (const float*)Av;
            float4 x0 = make_float4(0.f, 0.f, 0.f, 0.f), x1 = x0;
            if (rok) {
                x0 = *(const float4*)&Ax[(size_t)arow * 128 + kc * 32 + q * 8];
                x1 = *(const float4*)&Ax[(size_t)arow * 128 + kc * 32 + q * 8 + 4];
            }
            va[0] = x0.x; va[1] = x0.y; va[2] = x0.z; va[3] = x0.w;
            va[4] = x1.x; va[5] = x1.y; va[6] = x1.z; va[7] = x1.w;
        }
        if (AFFINE) {
            int cb = kc * 32 + q * 8;
            float4 g0 = *(float4*)&affg[cb], g1 = *(float4*)&affg[cb + 4];
            float4 b0 = *(float4*)&affb[cb], b1 = *(float4*)&affb[cb + 4];
            va[0] = fmaxf(va[0] * g0.x + b0.x, 0.f);
            va[1] = fmaxf(va[1] * g0.y + b0.y, 0.f);
            va[2] = fmaxf(va[2] * g0.z + b0.z, 0.f);
            va[3] = fmaxf(va[3] * g0.w + b0.w, 0.f);
            va[4] = fmaxf(va[4] * g1.x + b1.x, 0.f);
            va[5] = fmaxf(va[5] * g1.y + b1.y, 0.f);
            va[6] = fmaxf(va[6] * g1.z + b1.z, 0.f);
            va[7] = fmaxf(va[7] * g1.w + b1.w, 0.f);
        }
        uint4 au;
        au.x = bf16pack(va[0], va[1]);
        au.y = bf16pack(va[2], va[3]);
        au.z = bf16pack(va[4], va[5]);
        au.w = bf16pack(va[6], va[7]);
        s16x8 a = *(s16x8*)&au;
#pragma unroll
        for (int nt = 0; nt < 8; nt++) {
            s16x8 b = *(const s16x8*)&Wg[(((nt * 4 + kc) * 4 + q) * 16 + ml) * 8];
            acc[nt] = __builtin_amdgcn_mfma_f32_16x16x32_bf16(a, b, acc[nt], 0, 0, 0);
        }
    }

    // epilogue: two 64-col halves through LDS
    float csum[2][4] = {{0, 0, 0, 0}, {0, 0, 0, 0}};
    float csq[2][4] = {{0, 0, 0, 0}, {0, 0, 0, 0}};
    int cb = (t & 15) * 4;
#pragma unroll
    for (int h = 0; h < 2; ++h) {
        if (h) __syncthreads();  // protect chalf reuse
#pragma unroll
        for (int nt = 0; nt < 4; ++nt)
#pragma unroll
            for (int rr = 0; rr < 4; ++rr)
                chalf[(wv * 16 + q * 4 + rr) * 68 + nt * 16 + ml] = acc[h * 4 + nt][rr];
        __syncthreads();
        int c = h * 64 + cb;
#pragma unroll
        for (int it = 0; it < 4; ++it) {
            int r = (t >> 4) + it * 16;
            int row = row0 + r;
            if (row < n) {
                float4 v = *(float4*)&chalf[r * 68 + cb];
                if (!AFFINE) {
                    v.x += affg[c];
                    v.y += affg[c + 1];
                    v.z += affg[c + 2];
                    v.w += affg[c + 3];
                }
                if (STATS) {
                    csum[h][0] += v.x; csq[h][0] += v.x * v.x;
                    csum[h][1] += v.y; csq[h][1] += v.y * v.y;
                    csum[h][2] += v.z; csq[h][2] += v.z * v.z;
                    csum[h][3] += v.w; csq[h][3] += v.w * v.w;
                }
                float dv = SCALE ? dinv[row] : 1.0f;
                uint2 p;
                p.x = bf16pack(v.x * dv, v.y * dv);
                p.y = bf16pack(v.z * dv, v.w * dv);
                *(uint2*)&outv[(size_t)row * 64 + (c >> 1)] = p;
            }
        }
    }
    if (STATS) {
        __syncthreads();
        if (t < 128) { affg[t] = 0.f; affb[t] = 0.f; }
        __syncthreads();
#pragma unroll
        for (int h = 0; h < 2; ++h)
#pragma unroll
            for (int j = 0; j < 4; ++j) {
                atomicAdd(&affg[h * 64 + cb + j], csum[h][j]);
                atomicAdd(&affb[h * 64 + cb + j], csq[h][j]);
            }
        __syncthreads();
        if (t < 128) {
            atomicAdd(&stats_out[t], affg[t]);
            atomicAdd(&stats_out[128 + t], affb[t]);
        }
    }
}

// ---------------- fp32 GEMM (post FC only: 256 rows) ----------------
template <bool STATS, bool BIAS>
__global__ __launch_bounds__(256) void gemm128(const float* __restrict__ A, int n,
                                               const float* __restrict__ W,
                                               const float* __restrict__ bias,
                                               float* __restrict__ out,
                                               float* __restrict__ stats) {
    __shared__ float As[128][64];
    __shared__ float Ws[128][64];
    int tid = threadIdx.x;
    int row0 = blockIdx.y * 64;
    int col0 = blockIdx.x * 64;
    {
        int rsub = tid >> 5;
        int k4 = (tid & 31) * 4;
        for (int it = 0; it < 8; ++it) {
            int r = it * 8 + rsub;
            int row = row0 + r;
            float4 v = make_float4(0.f, 0.f, 0.f, 0.f);
            if (row < n) v = *(const float4*)&A[(size_t)row * 128 + k4];
            As[k4 + 0][r] = v.x;
            As[k4 + 1][r] = v.y;
            As[k4 + 2][r] = v.z;
            As[k4 + 3][r] = v.w;
        }
    }
    {
        int krow = tid >> 4;
        int c4 = (tid & 15) * 4;
        for (int it = 0; it < 8; ++it) {
            int k = it * 16 + krow;
            *(float4*)&Ws[k][c4] = *(const float4*)&W[k * 128 + col0 + c4];
        }
    }
    __syncthreads();
    int ty = tid >> 4, tx = tid & 15;
    float acc[4][4];
#pragma unroll
    for (int i = 0; i < 4; i++)
#pragma unroll
        for (int j = 0; j < 4; j++) acc[i][j] = 0.f;
#pragma unroll 4
    for (int k = 0; k < 128; k++) {
        float4 a = *(const float4*)&As[k][ty * 4];
        float4 b = *(const float4*)&Ws[k][tx * 4];
        float av[4] = {a.x, a.y, a.z, a.w};
        float bv[4] = {b.x, b.y, b.z, b.w};
#pragma unroll
        for (int i = 0; i < 4; i++)
#pragma unroll
            for (int j = 0; j < 4; j++) acc[i][j] += av[i] * bv[j];
    }
    float csum[4] = {0, 0, 0, 0}, csq[4] = {0, 0, 0, 0};
#pragma unroll
    for (int i = 0; i < 4; i++) {
        int row = row0 + ty * 4 + i;
        if (row < n) {
#pragma unroll
            for (int j = 0; j < 4; j++) {
                float v = acc[i][j];
                if (BIAS) v += bias[col0 + tx * 4 + j];
                out[(size_t)row * 128 + col0 + tx * 4 + j] = v;
                if (STATS) { csum[j] += v; csq[j] += v * v; }
            }
        }
    }
    if (STATS) {
        float* ps = &As[0][0];
        float* pq = &As[0][0] + 64;
        __syncthreads();
        if (tid < 64) { ps[tid] = 0.f; pq[tid] = 0.f; }
        __syncthreads();
#pragma unroll
        for (int j = 0; j < 4; j++) {
            atomicAdd(&ps[tx * 4 + j], csum[j]);
            atomicAdd(&pq[tx * 4 + j], csq[j]);
        }
        __syncthreads();
        if (tid < 64) {
            atomicAdd(&stats[col0 + tid], ps[tid]);
            atomicAdd(&stats[128 + col0 + tid], pq[tid]);
        }
    }
}

// ---------------- aggregation: 32-wide gather on h' = dinv*h ---------------------------
// out[i] = bf16( dinv[i]*( sum_e w_e*h'[src] + 2*h'[i] ) + bias )
// Latency x concurrency limited: 8->16-wide gave 71->64us (BW 1.94->2.10 TB/s, FETCH flat).
__global__ __launch_bounds__(256) void aggv_kernel(const unsigned* __restrict__ hT,
                                                   const int* __restrict__ rowptr,
                                                   const int* __restrict__ wsplit,
                                                   const unsigned* __restrict__ edat,
                                                   const float* __restrict__ dinv,
                                                   const float* __restrict__ convb,
                                                   unsigned* __restrict__ out,
                                                   float* __restrict__ stats) {
    __shared__ float sbuf[256];
    int t = threadIdx.x;
    int wave = t >> 6, lane = t & 63;
    int g = lane >> 4, u = lane & 15;
    int wid = blockIdx.x * 4 + wave;
    int i0 = wsplit[wid];
    int i1 = wsplit[wid + 1];
    float4 bb0 = *(const float4*)&convb[u * 8];
    float4 bb1 = *(const float4*)&convb[u * 8 + 4];
    float ssum[4] = {0, 0, 0, 0}, ssq[4] = {0, 0, 0, 0};
    for (int i = i0; i < i1; ++i) {
        int e = rowptr[i], end = rowptr[i + 1];
        uint4 hs = *(const uint4*)&hT[(size_t)i * 64 + u * 4];
        float di = dinv[i];
        float acc[8];
#pragma unroll
        for (int k = 0; k < 8; k++) acc[k] = 0.f;
        // 32 edges/iter: 8 independent edat loads + 8 independent row gathers in flight.
        for (int eb = e; eb < end; eb += 32) {
            unsigned dd[8];
            uint4 hv[8];
#pragma unroll
            for (int s = 0; s < 8; ++s) {
                int ee = eb + s * 4 + g;
                dd[s] = (ee < end) ? __builtin_nontemporal_load(edat + ee) : 0u;
            }
#pragma unroll
            for (int s = 0; s < 8; ++s)
                hv[s] = *(const uint4*)&hT[(size_t)(dd[s] & 0xFFFFu) * 64 + u * 4];
#pragma unroll
            for (int s = 0; s < 8; ++s) {
                float nrm = __uint_as_float(dd[s] & 0xFFFF0000u);
                float2 p0 = bf16unpack(hv[s].x), p1 = bf16unpack(hv[s].y);
                float2 p2 = bf16unpack(hv[s].z), p3 = bf16unpack(hv[s].w);
                acc[0] += nrm * p0.x; acc[1] += nrm * p0.y;
                acc[2] += nrm * p1.x; acc[3] += nrm * p1.y;
                acc[4] += nrm * p2.x; acc[5] += nrm * p2.y;
                acc[6] += nrm * p3.x; acc[7] += nrm * p3.y;
            }
        }
#pragma unroll
        for (int k = 0; k < 8; k++) {
            acc[k] += __shfl_xor(acc[k], 16);
            acc[k] += __shfl_xor(acc[k], 32);
        }
        {
            float2 p0 = bf16unpack(hs.x), p1 = bf16unpack(hs.y);
            float2 p2 = bf16unpack(hs.z), p3 = bf16unpack(hs.w);
            acc[0] += 2.f * p0.x; acc[1] += 2.f * p0.y;
            acc[2] += 2.f * p1.x; acc[3] += 2.f * p1.y;
            acc[4] += 2.f * p2.x; acc[5] += 2.f * p2.y;
            acc[6] += 2.f * p3.x; acc[7] += 2.f * p3.y;
        }
        if (g < 2) {
            float4 wv;
            if (g == 0)
                wv = make_float4(di * acc[0] + bb0.x, di * acc[1] + bb0.y,
                                 di * acc[2] + bb0.z, di * acc[3] + bb0.w);
            else
                wv = make_float4(di * acc[4] + bb1.x, di * acc[5] + bb1.y,
                                 di * acc[6] + bb1.z, di * acc[7] + bb1.w);
            ssum[0] += wv.x; ssq[0] += wv.x * wv.x;
            ssum[1] += wv.y; ssq[1] += wv.y * wv.y;
            ssum[2] += wv.z; ssq[2] += wv.z * wv.z;
            ssum[3] += wv.w; ssq[3] += wv.w * wv.w;
            uint2 p;
            p.x = bf16pack(wv.x, wv.y);
            p.y = bf16pack(wv.z, wv.w);
            *(uint2*)&out[(size_t)i * 64 + u * 4 + g * 2] = p;
        }
    }
    sbuf[t] = 0.f;
    __syncthreads();
    if (g < 2) {
        int f = u * 8 + g * 4;
#pragma unroll
        for (int j = 0; j < 4; j++) {
            atomicAdd(&sbuf[f + j], ssum[j]);
            atomicAdd(&sbuf[128 + f + j], ssq[j]);
        }
    }
    __syncthreads();
    atomicAdd(&stats[t], sbuf[t]);
}

// ---------------- pooling: one block per graph (batch sorted), atomic-free ----------------
// h is packed bf16 (64 u32/row)
__global__ __launch_bounds__(256) void pool2_kernel(const unsigned* __restrict__ h,
                                                    const float* __restrict__ stats_in,
                                                    const float* __restrict__ bn_sc,
                                                    const float* __restrict__ bn_bi,
                                                    const int* __restrict__ batch,
                                                    float* __restrict__ pooled) {
    int g = blockIdx.x;  // 0..GG-1
    int t = threadIdx.x;
    int f = t & 127, half = t >> 7;
    float mean = stats_in[f] * (1.0f / N_NODES);
    float var = fmaxf(stats_in[128 + f] * (1.0f / N_NODES) - mean * mean, 0.f);
    float ga = bn_sc[f] * rsqrtf(var + EPSV);
    float gb = bn_bi[f] - mean * ga;
    int lo, hi;
    {
        int a = 0, b = N_NODES;
        while (a < b) { int m = (a + b) >> 1; if (batch[m] < g) a = m + 1; else b = m; }
        lo = a;
        b = N_NODES;
        while (a < b) { int m = (a + b) >> 1; if (batch[m] < g + 1) a = m + 1; else b = m; }
        hi = a;
    }
    float acc = 0.f;
    for (int i = lo + half; i < hi; i += 2) {
        unsigned v = h[(size_t)i * 64 + (f >> 1)];
        float hv = (f & 1) ? __uint_as_float(v & 0xFFFF0000u) : __uint_as_float(v << 16);
        acc += fmaxf(hv * ga + gb, 0.f);
    }
    __shared__ float sb[256];
    sb[t] = acc;
    __syncthreads();
    if (t < 128)
        pooled[(size_t)g * 128 + t] = (sb[t] + sb[t + 128]) / fmaxf((float)(hi - lo), 1.0f);
}

// ---------------- output head: post-BN affine computed inline from stats5 ----------------
__global__ void out2_kernel(const float* __restrict__ Z, const float* __restrict__ stats5,
                            const float* __restrict__ bn_sc, const float* __restrict__ bn_bi,
                            const float* __restrict__ outW, const float* __restrict__ outb,
                            float* __restrict__ out) {
    int g = blockIdx.x;
    int lane = threadIdx.x;  // 64
    int d0 = lane * 2;
    const float invN = 1.0f / GG;
    float m0 = stats5[d0] * invN, m1 = stats5[d0 + 1] * invN;
    float v0 = fmaxf(stats5[128 + d0] * invN - m0 * m0, 0.f);
    float v1 = fmaxf(stats5[128 + d0 + 1] * invN - m1 * m1, 0.f);
    float ga0 = bn_sc[d0] * rsqrtf(v0 + EPSV), gb0 = bn_bi[d0] - m0 * ga0;
    float ga1 = bn_sc[d0 + 1] * rsqrtf(v1 + EPSV), gb1 = bn_bi[d0 + 1] - m1 * ga1;
    float2 z = *(const float2*)&Z[(size_t)g * 128 + d0];
    float s = fmaxf(z.x * ga0 + gb0, 0.f) * outW[d0] +
              fmaxf(z.y * ga1 + gb1, 0.f) * outW[d0 + 1];
    for (int off = 32; off; off >>= 1) s += __shfl_down(s, off);
    if (lane == 0) out[g] = s + outb[0];
}

// ---------------- host ----------------
extern "C" void kernel_launch(void* const* d_in, const int* in_sizes, int n_in,
                              void* d_out, int out_size, void* d_ws, size_t ws_size,
                              hipStream_t stream) {
    const float* x         = (const float*)d_in[0];
    const int*   ei        = (const int*)d_in[1];
    const float* ew        = (const float*)d_in[2];
    const int*   batch     = (const int*)d_in[3];
    const float* pre_W     = (const float*)d_in[4];
    const float* pre_b     = (const float*)d_in[5];
    const float* pre_bn_s  = (const float*)d_in[6];
    const float* pre_bn_b  = (const float*)d_in[7];
    const float* convW     = (const float*)d_in[8];
    const float* convb     = (const float*)d_in[9];
    const float* bn_s      = (const float*)d_in[10];
    const float* bn_b      = (const float*)d_in[11];
    const float* post_W    = (const float*)d_in[12];
    const float* post_b    = (const float*)d_in[13];
    const float* post_bn_s = (const float*)d_in[14];
    const float* post_bn_b = (const float*)d_in[15];
    const float* out_W     = (const float*)d_in[16];
    const float* out_b     = (const float*)d_in[17];

    float* ws = (float*)d_ws;
    unsigned long long* cd64 = (unsigned long long*)ws;  // N u64 = 2N floats (zeroed)
    float* stats  = ws + 2 * N_NODES;          // 6*256 (zeroed)
    size_t zero_floats = 2 * N_NODES + 6 * 256;
    float* pooled = stats + 6 * 256;           // 256*128 (fully written by pool2)
    float* Z      = pooled + GG * 128;         // 256*128 (fully written by gemm128)
    int*   rowptr = (int*)(Z + GG * 128);      // N+1
    int*   bsums  = rowptr + N_NODES + 1;      // NB
    int*   wsplit = bsums + NB;                // NWAVES+1
    int*   rank   = wsplit + NWAVES + 1;       // E
    size_t woff = (size_t)((float*)(rank + N_EDGES) - ws);
    woff = (woff + 3) & ~(size_t)3;            // 16B align for uint4
    unsigned short* Wf = (unsigned short*)(ws + woff);  // 5*16384 ushort = 40960 floats
    size_t eoff = woff + 40960;
    unsigned* edat = (unsigned*)(ws + eoff);   // E u32 (packed src|bf16w)
    float* dinv   = ws + eoff + (size_t)N_EDGES;  // N
    size_t off = eoff + (size_t)N_EDGES + N_NODES;
    off = (off + 3) & ~(size_t)3;              // 16B align
    unsigned* hA = (unsigned*)(ws + off);          // N*64 u32 packed bf16
    unsigned* hB = hA + (size_t)N_NODES * 64;      // N*64 u32 packed bf16

    hipMemsetAsync(d_ws, 0, zero_floats * sizeof(float), stream);
    prep_kernel<<<320 + 3125, 256, 0, stream>>>(pre_W, convW, Wf, ei, ew, cd64, rank);
    blocksum_kernel<<<NB, 256, 0, stream>>>(cd64, bsums);
    rowptr2_kernel<<<NB, 256, 0, stream>>>(cd64, bsums, rowptr, dinv);
    fillws_kernel<<<3125 + 17, 256, 0, stream>>>(ei, ew, rank, edat, rowptr, wsplit);

    // pre FC: hA = bf16(x @ pre_W + pre_b) (MFMA bf16), stats0 on fp32 values
    gemm_mfma<false, false, true, false><<<GEMM_BLOCKS, 256, 0, stream>>>(
        (const void*)x, N_NODES, (const uint4*)Wf, nullptr, nullptr, nullptr, pre_b, nullptr,
        hA, stats + 0);
    for (int l = 0; l < LL; l++) {
        const float* sc = (l == 0) ? pre_bn_s : bn_s + (l - 1) * 128;
        const float* bi = (l == 0) ? pre_bn_b : bn_b + (l - 1) * 128;
        // hB = bf16(dinv[row] * (relu(bn(hA)) @ convW[l]))  (h' = dinv*h)
        gemm_mfma<true, true, false, true><<<GEMM_BLOCKS, 256, 0, stream>>>(
            (const void*)hA, N_NODES, (const uint4*)(Wf + (size_t)(1 + l) * 16384),
            stats + l * 256, sc, bi, nullptr, dinv, hB, nullptr);
        // hA = bf16(dinv[i]*(gather(hB) + 2*h'[i]) + convb[l]), stats_{l+1}
        aggv_kernel<<<AGG_BLOCKS, 256, 0, stream>>>(hB, rowptr, wsplit, edat, dinv,
                                                    convb + l * 128, hA, stats + (l + 1) * 256);
    }
    // mean pool of relu(bn(hA)): one block per graph, atomic-free, divides inline
    pool2_kernel<<<GG, 256, 0, stream>>>(hA, stats + 4 * 256, bn_s + 3 * 128, bn_b + 3 * 128,
                                         batch, pooled);
    // post FC (fp32, tiny) + stats5
    dim3 gP(2, 4);
    gemm128<true, true><<<gP, 256, 0, stream>>>(pooled, GG, post_W, post_b, Z, stats + 5 * 256);
    // out head with inline post-BN affine
    out2_kernel<<<GG, 64, 0, stream>>>(Z, stats + 5 * 256, post_bn_s, post_bn_b, out_W, out_b,
                                       (float*)d_out);
}